// Round 1
// baseline (687.148 us; speedup 1.0000x reference)
//
#include <hip/hip_runtime.h>
#include <hip/hip_bf16.h>
#include <stdint.h>

// Problem dims (fixed)
#define NB 8
#define NS 2048
#define ND 1024
#define NH 4096
#define NE 8
#define NTOK (NB*NS)   // 16384 tokens

typedef __bf16 bf16;
typedef bf16 bf16x8 __attribute__((ext_vector_type(8)));
typedef float f32x4 __attribute__((ext_vector_type(4)));

// ws layout (bytes):
//   [0, 2KB)        : int meta[512]
//        meta[0..7]   counts
//        meta[8..15]  cursors
//        meta[16..24] offs (exclusive prefix)
//        meta[25]     nTiles
//        meta[32..191]  tileExpert
//        meta[192..351] tileRowStart
//        meta[352..511] tileRowCount
//   [2KB, ...)      : int perm[16384]  (= meta+512)
//   OFF_XB  : bf16 xb [NTOK][ND]      32MB
//   OFF_WTE : bf16 wte[NE][NH][ND]    64MB   (W_e transposed per expert)
//   OFF_WTO : bf16 wto[ND][NH]         8MB   (W_out transposed)
//   OFF_HB  : bf16 hb [NTOK][NH]     128MB   (relu hidden)
// total ~232.1 MB
static const size_t OFF_XB  = 128 * 1024;
static const size_t OFF_WTE = OFF_XB  + (size_t)NTOK * ND * 2;
static const size_t OFF_WTO = OFF_WTE + (size_t)NE * NH * ND * 2;
static const size_t OFF_HB  = OFF_WTO + (size_t)ND * NH * 2;
static const size_t WS_NEED = OFF_HB  + (size_t)NTOK * NH * 2;

#define GLDS16(src, dst) __builtin_amdgcn_global_load_lds( \
    (__attribute__((address_space(1))) void*)(void*)(src), \
    (__attribute__((address_space(3))) void*)(dst), 16, 0, 0)

// ---------------- prep kernels ----------------

__global__ void k_cvt_x(const float* __restrict__ in, bf16* __restrict__ out) {
    long i = (long)blockIdx.x * blockDim.x + threadIdx.x;   // each handles 8 floats
    const float4* in4 = (const float4*)in;
    float4 v0 = in4[i * 2];
    float4 v1 = in4[i * 2 + 1];
    bf16x8 o;
    o[0] = (bf16)v0.x; o[1] = (bf16)v0.y; o[2] = (bf16)v0.z; o[3] = (bf16)v0.w;
    o[4] = (bf16)v1.x; o[5] = (bf16)v1.y; o[6] = (bf16)v1.z; o[7] = (bf16)v1.w;
    *(bf16x8*)(out + i * 8) = o;
}

__global__ void k_hist(const int* __restrict__ assign, int* __restrict__ meta) {
    int t = blockIdx.x * blockDim.x + threadIdx.x;
    if (t < NTOK) atomicAdd(&meta[assign[t] & 7], 1);
}

__global__ void k_desc(int* __restrict__ meta) {
    if (threadIdx.x != 0 || blockIdx.x != 0) return;
    int* counts = meta;
    int* offs = meta + 16;
    offs[0] = 0;
    for (int e = 0; e < NE; e++) offs[e + 1] = offs[e] + counts[e];
    int* te  = meta + 32;
    int* trs = meta + 192;
    int* trc = meta + 352;
    int nt = 0;
    for (int e = 0; e < NE; e++) {
        int c = counts[e];
        for (int t0 = 0; t0 < c; t0 += 128) {
            te[nt] = e; trs[nt] = offs[e] + t0; trc[nt] = min(128, c - t0);
            nt++;
        }
    }
    meta[25] = nt;
}

__global__ void k_scatter(const int* __restrict__ assign, int* __restrict__ meta) {
    int t = blockIdx.x * blockDim.x + threadIdx.x;
    if (t < NTOK) {
        int e = assign[t] & 7;
        int p = atomicAdd(&meta[8 + e], 1);
        int* perm = meta + 512;
        perm[meta[16 + e] + p] = t;
    }
}

// transpose+convert: in [batch][R][C] f32 -> out [batch][C][R] bf16
__global__ void k_transpose(const float* __restrict__ in, bf16* __restrict__ out,
                            int R, int C) {
    __shared__ float tile[32][33];
    int b  = blockIdx.z;
    int c0 = blockIdx.x * 32, r0 = blockIdx.y * 32;
    const float* inb = in + (size_t)b * R * C;
    bf16* outb = out + (size_t)b * R * C;
    int tx = threadIdx.x, ty = threadIdx.y;   // 32 x 8
#pragma unroll
    for (int i = 0; i < 4; i++) {
        int r = r0 + ty + i * 8;
        tile[ty + i * 8][tx] = inb[(size_t)r * C + c0 + tx];
    }
    __syncthreads();
#pragma unroll
    for (int i = 0; i < 4; i++) {
        int c = c0 + ty + i * 8;   // output row index (original col)
        outb[(size_t)c * R + r0 + tx] = (bf16)tile[tx][ty + i * 8];
    }
}

// ---------------- GEMM 1: h = relu(gather(x) @ W_e[e] + b_e[e]) ----------------
// A: xb rows gathered via perm (bf16, [*][ND]); B: wte[e] as [NH][ND] (N-major, K-contig)
// C: hb[token][NH] bf16, scattered back via perm.
__launch_bounds__(256)
__global__ void k_gemm1(const bf16* __restrict__ xb, const bf16* __restrict__ wte,
                        const float* __restrict__ b_e, bf16* __restrict__ hb,
                        const int* __restrict__ meta) {
    int nt = meta[25];
    int tileIdx = blockIdx.y;
    if (tileIdx >= nt) return;
    int e  = meta[32 + tileIdx];
    int rs = meta[192 + tileIdx];
    int rc = meta[352 + tileIdx];
    const int* perm = meta + 512;
    int n0 = blockIdx.x * 128;

    __shared__ __align__(16) bf16 As[128][32];
    __shared__ __align__(16) bf16 Bs[128][32];

    int t = threadIdx.x;
    int lane = t & 63, w = t >> 6;
    int srow  = t >> 2;          // 0..63 staging row
    int scol8 = (t & 3) * 8;     // staging col (elements)

    int tok0 = perm[rs + min(srow,      rc - 1)];
    int tok1 = perm[rs + min(srow + 64, rc - 1)];
    const bf16* a0 = xb + (size_t)tok0 * ND + scol8;
    const bf16* a1 = xb + (size_t)tok1 * ND + scol8;
    const bf16* bb = wte + ((size_t)e * NH + n0) * ND + scol8;
    const bf16* b0 = bb + (size_t)srow * ND;
    const bf16* b1 = bb + (size_t)(srow + 64) * ND;

    char* asBase = (char*)&As[0][0] + w * 1024;  // wave-uniform; HW adds lane*16
    char* bsBase = (char*)&Bs[0][0] + w * 1024;

    f32x4 acc[4][4] = {};
    int wm = w >> 1, wn = w & 1;
    int lr = lane & 15, lk = (lane >> 4) * 8;

    for (int k0 = 0; k0 < ND; k0 += 32) {
        GLDS16(a0 + k0, asBase);
        GLDS16(a1 + k0, asBase + 4096);
        GLDS16(b0 + k0, bsBase);
        GLDS16(b1 + k0, bsBase + 4096);
        __syncthreads();
        bf16x8 af[4], bfr[4];
#pragma unroll
        for (int m = 0; m < 4; m++) af[m]  = *(const bf16x8*)&As[wm * 64 + m * 16 + lr][lk];
#pragma unroll
        for (int n = 0; n < 4; n++) bfr[n] = *(const bf16x8*)&Bs[wn * 64 + n * 16 + lr][lk];
#pragma unroll
        for (int m = 0; m < 4; m++)
#pragma unroll
            for (int n = 0; n < 4; n++)
                acc[m][n] = __builtin_amdgcn_mfma_f32_16x16x32_bf16(af[m], bfr[n], acc[m][n], 0, 0, 0);
        __syncthreads();
    }

#pragma unroll
    for (int m = 0; m < 4; m++)
#pragma unroll
        for (int n = 0; n < 4; n++) {
            int gc = n0 + wn * 64 + n * 16 + lr;
            float bias = b_e[e * NH + gc];
#pragma unroll
            for (int r = 0; r < 4; r++) {
                int row = wm * 64 + m * 16 + ((lane >> 4) << 2) + r;
                if (row < rc) {
                    int tok = perm[rs + row];
                    float v = fmaxf(acc[m][n][r] + bias, 0.0f);
                    hb[(size_t)tok * NH + gc] = (bf16)v;
                }
            }
        }
}

// ---------------- GEMM 2: out = hb @ W_out + b_out (dense) ----------------
// A: hb [NTOK][NH] bf16; B: wto [ND][NH] (N-major, K-contig); C: out f32 [NTOK][ND]
__launch_bounds__(256)
__global__ void k_gemm2(const bf16* __restrict__ hb, const bf16* __restrict__ wto,
                        const float* __restrict__ b_out, float* __restrict__ out) {
    int m0 = blockIdx.y * 128;
    int n0 = blockIdx.x * 128;

    __shared__ __align__(16) bf16 As[128][32];
    __shared__ __align__(16) bf16 Bs[128][32];

    int t = threadIdx.x;
    int lane = t & 63, w = t >> 6;
    int srow  = t >> 2;
    int scol8 = (t & 3) * 8;

    const bf16* a0 = hb + (size_t)(m0 + srow) * NH + scol8;
    const bf16* a1 = hb + (size_t)(m0 + srow + 64) * NH + scol8;
    const bf16* b0 = wto + (size_t)(n0 + srow) * NH + scol8;
    const bf16* b1 = wto + (size_t)(n0 + srow + 64) * NH + scol8;

    char* asBase = (char*)&As[0][0] + w * 1024;
    char* bsBase = (char*)&Bs[0][0] + w * 1024;

    f32x4 acc[4][4] = {};
    int wm = w >> 1, wn = w & 1;
    int lr = lane & 15, lk = (lane >> 4) * 8;

    for (int k0 = 0; k0 < NH; k0 += 32) {
        GLDS16(a0 + k0, asBase);
        GLDS16(a1 + k0, asBase + 4096);
        GLDS16(b0 + k0, bsBase);
        GLDS16(b1 + k0, bsBase + 4096);
        __syncthreads();
        bf16x8 af[4], bfr[4];
#pragma unroll
        for (int m = 0; m < 4; m++) af[m]  = *(const bf16x8*)&As[wm * 64 + m * 16 + lr][lk];
#pragma unroll
        for (int n = 0; n < 4; n++) bfr[n] = *(const bf16x8*)&Bs[wn * 64 + n * 16 + lr][lk];
#pragma unroll
        for (int m = 0; m < 4; m++)
#pragma unroll
            for (int n = 0; n < 4; n++)
                acc[m][n] = __builtin_amdgcn_mfma_f32_16x16x32_bf16(af[m], bfr[n], acc[m][n], 0, 0, 0);
        __syncthreads();
    }

#pragma unroll
    for (int m = 0; m < 4; m++)
#pragma unroll
        for (int n = 0; n < 4; n++) {
            int gc = n0 + wn * 64 + n * 16 + lr;
            float bias = b_out[gc];
#pragma unroll
            for (int r = 0; r < 4; r++) {
                int row = m0 + wm * 64 + m * 16 + ((lane >> 4) << 2) + r;
                out[(size_t)row * ND + gc] = acc[m][n][r] + bias;
            }
        }
}

extern "C" void kernel_launch(void* const* d_in, const int* in_sizes, int n_in,
                              void* d_out, int out_size, void* d_ws, size_t ws_size,
                              hipStream_t stream) {
    const float* x     = (const float*)d_in[0];
    const float* W_e   = (const float*)d_in[1];
    const float* b_e   = (const float*)d_in[2];
    const float* W_out = (const float*)d_in[3];
    const float* b_out = (const float*)d_in[4];
    const int*   assign = (const int*)d_in[5];
    float* out = (float*)d_out;

    if (ws_size < WS_NEED) return;  // need ~232MB scratch

    char* ws = (char*)d_ws;
    int*  meta = (int*)ws;
    bf16* xb  = (bf16*)(ws + OFF_XB);
    bf16* wte = (bf16*)(ws + OFF_WTE);
    bf16* wto = (bf16*)(ws + OFF_WTO);
    bf16* hb  = (bf16*)(ws + OFF_HB);

    hipMemsetAsync(meta, 0, 512 * sizeof(int), stream);

    // convert x to bf16: 16777216 elems / (256 thr * 8) = 8192 blocks
    k_cvt_x<<<NTOK * ND / (256 * 8), 256, 0, stream>>>(x, xb);
    // routing metadata
    k_hist<<<NTOK / 256, 256, 0, stream>>>(assign, meta);
    k_desc<<<1, 64, 0, stream>>>(meta);
    k_scatter<<<NTOK / 256, 256, 0, stream>>>(assign, meta);
    // transpose weights to [N][K] bf16
    k_transpose<<<dim3(NH / 32, ND / 32, NE), dim3(32, 8), 0, stream>>>(W_e, wte, ND, NH);
    k_transpose<<<dim3(ND / 32, NH / 32, 1), dim3(32, 8), 0, stream>>>(W_out, wto, NH, ND);
    // grouped GEMM1: max tiles = 16384/128 + 8 = 136
    k_gemm1<<<dim3(NH / 128, 136), 256, 0, stream>>>(xb, wte, b_e, hb, meta);
    // dense GEMM2
    k_gemm2<<<dim3(ND / 128, NTOK / 128), 256, 0, stream>>>(hb, wto, b_out, out);
}

// Round 2
// 509.338 us; speedup vs baseline: 1.3491x; 1.3491x over previous
//
#include <hip/hip_runtime.h>
#include <hip/hip_bf16.h>
#include <stdint.h>

// Problem dims (fixed)
#define NB 8
#define NS 2048
#define ND 1024
#define NH 4096
#define NE 8
#define NTOK (NB*NS)   // 16384 tokens

typedef __bf16 bf16;
typedef bf16 bf16x8 __attribute__((ext_vector_type(8)));
typedef float f32x4 __attribute__((ext_vector_type(4)));

// ws layout (bytes):
//   meta[512] ints: counts[0..7] cursors[8..15] offs[16..24] nTiles[25]
//                   tileExpert[32..103] tileRowStart[128..199] tileRowCount[256..327]
//   perm[16384] at meta+512
//   OFF_XB  : bf16 xb [NTOK][ND]      32MB
//   OFF_WTE : bf16 wte[NE][NH][ND]    64MB   (W_e transposed per expert, [n][k])
//   OFF_WTO : bf16 wto[ND][NH]         8MB   (W_out transposed, [n][k])
//   OFF_HB  : bf16 hb [NTOK][NH]     128MB   (relu hidden, PERMUTED row order)
static const size_t OFF_XB  = 128 * 1024;
static const size_t OFF_WTE = OFF_XB  + (size_t)NTOK * ND * 2;
static const size_t OFF_WTO = OFF_WTE + (size_t)NE * NH * ND * 2;
static const size_t OFF_HB  = OFF_WTO + (size_t)ND * NH * 2;
static const size_t WS_NEED = OFF_HB  + (size_t)NTOK * NH * 2;

#define GLDS16(src, dst) __builtin_amdgcn_global_load_lds( \
    (__attribute__((address_space(1))) void*)(void*)(src), \
    (__attribute__((address_space(3))) void*)(dst), 16, 0, 0)

// ---------------- prep kernels ----------------

__global__ void k_cvt_x(const float* __restrict__ in, bf16* __restrict__ out) {
    long i = (long)blockIdx.x * blockDim.x + threadIdx.x;   // 8 floats each
    const float4* in4 = (const float4*)in;
    float4 v0 = in4[i * 2];
    float4 v1 = in4[i * 2 + 1];
    bf16x8 o;
    o[0] = (bf16)v0.x; o[1] = (bf16)v0.y; o[2] = (bf16)v0.z; o[3] = (bf16)v0.w;
    o[4] = (bf16)v1.x; o[5] = (bf16)v1.y; o[6] = (bf16)v1.z; o[7] = (bf16)v1.w;
    *(bf16x8*)(out + i * 8) = o;
}

__global__ void k_hist(const int* __restrict__ assign, int* __restrict__ meta) {
    int t = blockIdx.x * blockDim.x + threadIdx.x;
    if (t < NTOK) atomicAdd(&meta[assign[t] & 7], 1);
}

__global__ void k_desc(int* __restrict__ meta) {
    if (threadIdx.x != 0 || blockIdx.x != 0) return;
    int* counts = meta;
    int* offs = meta + 16;
    offs[0] = 0;
    for (int e = 0; e < NE; e++) offs[e + 1] = offs[e] + counts[e];
    int* te  = meta + 32;
    int* trs = meta + 128;
    int* trc = meta + 256;
    int nt = 0;
    for (int e = 0; e < NE; e++) {
        int c = counts[e];
        for (int t0 = 0; t0 < c; t0 += 256) {
            te[nt] = e; trs[nt] = offs[e] + t0; trc[nt] = min(256, c - t0);
            nt++;
        }
    }
    meta[25] = nt;
}

__global__ void k_scatter(const int* __restrict__ assign, int* __restrict__ meta) {
    int t = blockIdx.x * blockDim.x + threadIdx.x;
    if (t < NTOK) {
        int e = assign[t] & 7;
        int p = atomicAdd(&meta[8 + e], 1);
        int* perm = meta + 512;
        perm[meta[16 + e] + p] = t;
    }
}

// transpose+convert: in [batch][R][C] f32 -> out [batch][C][R] bf16
__global__ void k_transpose(const float* __restrict__ in, bf16* __restrict__ out,
                            int R, int C) {
    __shared__ float tile[32][33];
    int b  = blockIdx.z;
    int c0 = blockIdx.x * 32, r0 = blockIdx.y * 32;
    const float* inb = in + (size_t)b * R * C;
    bf16* outb = out + (size_t)b * R * C;
    int tx = threadIdx.x, ty = threadIdx.y;   // 32 x 8
#pragma unroll
    for (int i = 0; i < 4; i++) {
        int r = r0 + ty + i * 8;
        tile[ty + i * 8][tx] = inb[(size_t)r * C + c0 + tx];
    }
    __syncthreads();
#pragma unroll
    for (int i = 0; i < 4; i++) {
        int c = c0 + ty + i * 8;
        outb[(size_t)c * R + r0 + tx] = (bf16)tile[tx][ty + i * 8];
    }
}

// =====================================================================
// 256x256 tile, BK=32, 8 waves (2Mx4N), 4-deep LDS ring, counted vmcnt.
// LDS buffer (32KB): A[256 rows][32 k] bf16 at +0, B[256 n][32 k] at +16KB.
// Swizzle: 16B granule g of row r stored at slot s = g ^ ((r>>1)&3).
//   bank check: lanes 0-15 (rows r..r+15, same g) -> 2-way only (free).
// Staging (linear LDS, wave-uniform dst): thread tid round rr covers
//   srow = rr*128 + tid/4, slot sgr = tid&3 -> loads global granule
//   sgr ^ ((srow>>1)&3).  Read at granule kg uses slot kg ^ ((row>>1)&3).
// Pipeline: stage(t+2) | ds_read(t) | 32 MFMA | vmcnt(4) barrier.
// =====================================================================

__launch_bounds__(512, 2)
__global__ void k_gemm1(const bf16* __restrict__ xb, const bf16* __restrict__ wte,
                        const float* __restrict__ b_e, bf16* __restrict__ hb,
                        const int* __restrict__ meta) {
    __shared__ __align__(16) char sm[4 * 32768];
    int nt = meta[25];
    int tileIdx = blockIdx.y;
    if (tileIdx >= nt) return;
    int e  = meta[32 + tileIdx];
    int rs = meta[128 + tileIdx];
    int rc = meta[256 + tileIdx];
    const int* perm = meta + 512;
    int n0 = blockIdx.x * 256;

    int tid = threadIdx.x;
    int lane = tid & 63, wid = tid >> 6;
    int wr = wid >> 2, wc = wid & 3;          // 2 x 4 wave grid
    int lr = lane & 15, kg = lane >> 4;
    int sg = kg ^ ((lr >> 1) & 3);            // swizzled read granule

    // staging sources
    int srow0 = tid >> 2, srow1 = 128 + srow0;
    int sgr   = tid & 3;
    int gg0 = sgr ^ ((srow0 >> 1) & 3);
    int gg1 = sgr ^ ((srow1 >> 1) & 3);
    int t0i = rs + (srow0 < rc - 1 ? srow0 : rc - 1);
    int t1i = rs + (srow1 < rc - 1 ? srow1 : rc - 1);
    const bf16* a0 = xb + (size_t)perm[t0i] * ND + gg0 * 8;
    const bf16* a1 = xb + (size_t)perm[t1i] * ND + gg1 * 8;
    const bf16* wb = wte + ((size_t)e * NH + n0) * ND;
    const bf16* b0 = wb + (size_t)srow0 * ND + gg0 * 8;
    const bf16* b1 = wb + (size_t)srow1 * ND + gg1 * 8;

#define STAGE1(kt) { char* bb = sm + ((kt) & 3) * 32768; int ko = (kt) * 32; \
    GLDS16(a0 + ko, bb + wid * 1024); \
    GLDS16(a1 + ko, bb + 8192 + wid * 1024); \
    GLDS16(b0 + ko, bb + 16384 + wid * 1024); \
    GLDS16(b1 + ko, bb + 24576 + wid * 1024); }

    f32x4 acc[8][4] = {};
    const int NT = ND / 32;   // 32
    STAGE1(0); STAGE1(1);
    asm volatile("s_waitcnt vmcnt(4)" ::: "memory");
    __builtin_amdgcn_s_barrier();
    asm volatile("" ::: "memory");

    for (int t = 0; t < NT; ++t) {
        if (t + 2 < NT) STAGE1(t + 2);
        char* bc = sm + (t & 3) * 32768;
        bf16x8 af[8], bfr[4];
#pragma unroll
        for (int n = 0; n < 4; n++)
            bfr[n] = *(const bf16x8*)(bc + 16384 + (wc * 64 + n * 16 + lr) * 64 + sg * 16);
#pragma unroll
        for (int m = 0; m < 8; m++)
            af[m] = *(const bf16x8*)(bc + (wr * 128 + m * 16 + lr) * 64 + sg * 16);
        __builtin_amdgcn_s_setprio(1);
#pragma unroll
        for (int m = 0; m < 8; m++)
#pragma unroll
            for (int n = 0; n < 4; n++)
                acc[m][n] = __builtin_amdgcn_mfma_f32_16x16x32_bf16(af[m], bfr[n], acc[m][n], 0, 0, 0);
        __builtin_amdgcn_s_setprio(0);
        if (t + 1 < NT) {
            if (t + 2 < NT) { asm volatile("s_waitcnt vmcnt(4)" ::: "memory"); }
            else            { asm volatile("s_waitcnt vmcnt(0)" ::: "memory"); }
            __builtin_amdgcn_s_barrier();
            asm volatile("" ::: "memory");
        }
    }

    // epilogue: bias + relu, bf16, PERMUTED row order (dense rows rs..rs+rc)
    float bias[4];
#pragma unroll
    for (int n = 0; n < 4; n++) bias[n] = b_e[e * NH + n0 + wc * 64 + n * 16 + lr];
#pragma unroll
    for (int m = 0; m < 8; m++) {
#pragma unroll
        for (int r = 0; r < 4; r++) {
            int row = wr * 128 + m * 16 + (lane >> 4) * 4 + r;
            if (row < rc) {
                bf16* hp = hb + (size_t)(rs + row) * NH + n0 + wc * 64;
#pragma unroll
                for (int n = 0; n < 4; n++)
                    hp[n * 16 + lr] = (bf16)fmaxf(acc[m][n][r] + bias[n], 0.0f);
            }
        }
    }
#undef STAGE1
}

__launch_bounds__(512, 2)
__global__ void k_gemm2(const bf16* __restrict__ hb, const bf16* __restrict__ wto,
                        const float* __restrict__ b_out, const int* __restrict__ meta,
                        float* __restrict__ out) {
    __shared__ __align__(16) char sm[4 * 32768];
    // XCD-aware swizzle: 256 blocks exactly, 32 per XCD chunk
    int lin = blockIdx.x;
    int swz = (lin & 7) * 32 + (lin >> 3);
    int bx = swz & 3, by = swz >> 2;          // 4 n-blocks x 64 m-blocks
    int m0 = by * 256, n0 = bx * 256;
    const int* perm = meta + 512;

    int tid = threadIdx.x;
    int lane = tid & 63, wid = tid >> 6;
    int wr = wid >> 2, wc = wid & 3;
    int lr = lane & 15, kg = lane >> 4;
    int sg = kg ^ ((lr >> 1) & 3);

    int srow0 = tid >> 2, srow1 = 128 + srow0;
    int sgr   = tid & 3;
    int gg0 = sgr ^ ((srow0 >> 1) & 3);
    int gg1 = sgr ^ ((srow1 >> 1) & 3);
    const bf16* a0 = hb + (size_t)(m0 + srow0) * NH + gg0 * 8;
    const bf16* a1 = hb + (size_t)(m0 + srow1) * NH + gg1 * 8;
    const bf16* b0 = wto + (size_t)(n0 + srow0) * NH + gg0 * 8;
    const bf16* b1 = wto + (size_t)(n0 + srow1) * NH + gg1 * 8;

#define STAGE2(kt) { char* bb = sm + ((kt) & 3) * 32768; int ko = (kt) * 32; \
    GLDS16(a0 + ko, bb + wid * 1024); \
    GLDS16(a1 + ko, bb + 8192 + wid * 1024); \
    GLDS16(b0 + ko, bb + 16384 + wid * 1024); \
    GLDS16(b1 + ko, bb + 24576 + wid * 1024); }

    f32x4 acc[8][4] = {};
    const int NT = NH / 32;   // 128
    STAGE2(0); STAGE2(1);
    asm volatile("s_waitcnt vmcnt(4)" ::: "memory");
    __builtin_amdgcn_s_barrier();
    asm volatile("" ::: "memory");

    for (int t = 0; t < NT; ++t) {
        if (t + 2 < NT) STAGE2(t + 2);
        char* bc = sm + (t & 3) * 32768;
        bf16x8 af[8], bfr[4];
#pragma unroll
        for (int n = 0; n < 4; n++)
            bfr[n] = *(const bf16x8*)(bc + 16384 + (wc * 64 + n * 16 + lr) * 64 + sg * 16);
#pragma unroll
        for (int m = 0; m < 8; m++)
            af[m] = *(const bf16x8*)(bc + (wr * 128 + m * 16 + lr) * 64 + sg * 16);
        __builtin_amdgcn_s_setprio(1);
#pragma unroll
        for (int m = 0; m < 8; m++)
#pragma unroll
            for (int n = 0; n < 4; n++)
                acc[m][n] = __builtin_amdgcn_mfma_f32_16x16x32_bf16(af[m], bfr[n], acc[m][n], 0, 0, 0);
        __builtin_amdgcn_s_setprio(0);
        if (t + 1 < NT) {
            if (t + 2 < NT) { asm volatile("s_waitcnt vmcnt(4)" ::: "memory"); }
            else            { asm volatile("s_waitcnt vmcnt(0)" ::: "memory"); }
            __builtin_amdgcn_s_barrier();
            asm volatile("" ::: "memory");
        }
    }

    // epilogue: bias add, scatter rows back to token order via perm
    float bias[4];
#pragma unroll
    for (int n = 0; n < 4; n++) bias[n] = b_out[n0 + wc * 64 + n * 16 + lr];
#pragma unroll
    for (int m = 0; m < 8; m++) {
#pragma unroll
        for (int r = 0; r < 4; r++) {
            int prow = m0 + wr * 128 + m * 16 + (lane >> 4) * 4 + r;
            int tok = perm[prow];
            float* op = out + (size_t)tok * ND + n0 + wc * 64;
#pragma unroll
            for (int n = 0; n < 4; n++)
                op[n * 16 + lr] = acc[m][n][r] + bias[n];
        }
    }
#undef STAGE2
}

extern "C" void kernel_launch(void* const* d_in, const int* in_sizes, int n_in,
                              void* d_out, int out_size, void* d_ws, size_t ws_size,
                              hipStream_t stream) {
    const float* x     = (const float*)d_in[0];
    const float* W_e   = (const float*)d_in[1];
    const float* b_e   = (const float*)d_in[2];
    const float* W_out = (const float*)d_in[3];
    const float* b_out = (const float*)d_in[4];
    const int*   assign = (const int*)d_in[5];
    float* out = (float*)d_out;

    if (ws_size < WS_NEED) return;

    char* ws = (char*)d_ws;
    int*  meta = (int*)ws;
    bf16* xb  = (bf16*)(ws + OFF_XB);
    bf16* wte = (bf16*)(ws + OFF_WTE);
    bf16* wto = (bf16*)(ws + OFF_WTO);
    bf16* hb  = (bf16*)(ws + OFF_HB);

    hipMemsetAsync(meta, 0, 512 * sizeof(int), stream);

    k_cvt_x<<<NTOK * ND / (256 * 8), 256, 0, stream>>>(x, xb);
    k_hist<<<NTOK / 256, 256, 0, stream>>>(assign, meta);
    k_desc<<<1, 64, 0, stream>>>(meta);
    k_scatter<<<NTOK / 256, 256, 0, stream>>>(assign, meta);
    k_transpose<<<dim3(NH / 32, ND / 32, NE), dim3(32, 8), 0, stream>>>(W_e, wte, ND, NH);
    k_transpose<<<dim3(ND / 32, NH / 32, 1), dim3(32, 8), 0, stream>>>(W_out, wto, NH, ND);
    // grouped GEMM1: max tiles = 16384/256 + 8 = 72
    k_gemm1<<<dim3(NH / 256, 72), 512, 0, stream>>>(xb, wte, b_e, hb, meta);
    // dense GEMM2 over permuted hb rows, scatter at the end
    k_gemm2<<<256, 512, 0, stream>>>(hb, wto, b_out, meta, out);
}

// Round 3
// 492.965 us; speedup vs baseline: 1.3939x; 1.0332x over previous
//
#include <hip/hip_runtime.h>
#include <hip/hip_bf16.h>
#include <stdint.h>

// Problem dims (fixed)
#define NB 8
#define NS 2048
#define ND 1024
#define NH 4096
#define NE 8
#define NTOK (NB*NS)   // 16384 tokens

typedef __bf16 bf16;
typedef bf16 bf16x8 __attribute__((ext_vector_type(8)));
typedef float f32x4 __attribute__((ext_vector_type(4)));

// ws layout: meta[512] ints + perm[16384] at meta+512, then:
static const size_t OFF_XB  = 128 * 1024;                          // bf16 xb [NTOK][ND]
static const size_t OFF_WTE = OFF_XB  + (size_t)NTOK * ND * 2;     // bf16 wte[NE][NH][ND]
static const size_t OFF_WTO = OFF_WTE + (size_t)NE * NH * ND * 2;  // bf16 wto[ND][NH]
static const size_t OFF_HB  = OFF_WTO + (size_t)ND * NH * 2;       // bf16 hb [NTOK][NH] (permuted rows)
static const size_t WS_NEED = OFF_HB  + (size_t)NTOK * NH * 2;

#define GLDS16(src, dst) __builtin_amdgcn_global_load_lds( \
    (__attribute__((address_space(1))) void*)(void*)(src), \
    (__attribute__((address_space(3))) void*)(dst), 16, 0, 0)

// ---------------- prep kernels ----------------

__global__ void k_cvt_x(const float* __restrict__ in, bf16* __restrict__ out) {
    long i = (long)blockIdx.x * blockDim.x + threadIdx.x;
    const float4* in4 = (const float4*)in;
    float4 v0 = in4[i * 2];
    float4 v1 = in4[i * 2 + 1];
    bf16x8 o;
    o[0] = (bf16)v0.x; o[1] = (bf16)v0.y; o[2] = (bf16)v0.z; o[3] = (bf16)v0.w;
    o[4] = (bf16)v1.x; o[5] = (bf16)v1.y; o[6] = (bf16)v1.z; o[7] = (bf16)v1.w;
    *(bf16x8*)(out + i * 8) = o;
}

__global__ void k_hist(const int* __restrict__ assign, int* __restrict__ meta) {
    int t = blockIdx.x * blockDim.x + threadIdx.x;
    if (t < NTOK) atomicAdd(&meta[assign[t] & 7], 1);
}

__global__ void k_desc(int* __restrict__ meta) {
    if (threadIdx.x != 0 || blockIdx.x != 0) return;
    int* counts = meta;
    int* offs = meta + 16;
    offs[0] = 0;
    for (int e = 0; e < NE; e++) offs[e + 1] = offs[e] + counts[e];
    int* te  = meta + 32;
    int* trs = meta + 128;
    int* trc = meta + 256;
    int nt = 0;
    for (int e = 0; e < NE; e++) {
        int c = counts[e];
        for (int t0 = 0; t0 < c; t0 += 256) {
            te[nt] = e; trs[nt] = offs[e] + t0; trc[nt] = min(256, c - t0);
            nt++;
        }
    }
    meta[25] = nt;
}

__global__ void k_scatter(const int* __restrict__ assign, int* __restrict__ meta) {
    int t = blockIdx.x * blockDim.x + threadIdx.x;
    if (t < NTOK) {
        int e = assign[t] & 7;
        int p = atomicAdd(&meta[8 + e], 1);
        int* perm = meta + 512;
        perm[meta[16 + e] + p] = t;
    }
}

// transpose+convert: in [batch][R][C] f32 -> out [batch][C][R] bf16
__global__ void k_transpose(const float* __restrict__ in, bf16* __restrict__ out,
                            int R, int C) {
    __shared__ float tile[32][33];
    int b  = blockIdx.z;
    int c0 = blockIdx.x * 32, r0 = blockIdx.y * 32;
    const float* inb = in + (size_t)b * R * C;
    bf16* outb = out + (size_t)b * R * C;
    int tx = threadIdx.x, ty = threadIdx.y;
#pragma unroll
    for (int i = 0; i < 4; i++) {
        int r = r0 + ty + i * 8;
        tile[ty + i * 8][tx] = inb[(size_t)r * C + c0 + tx];
    }
    __syncthreads();
#pragma unroll
    for (int i = 0; i < 4; i++) {
        int c = c0 + ty + i * 8;
        outb[(size_t)c * R + r0 + tx] = (bf16)tile[tx][ty + i * 8];
    }
}

// =====================================================================
// 8-phase 256x256 GEMM template (m201-style), BK=64, 8 waves (2Mx4N).
// LDS: 2 dbuf x 64KB; regions per dbuf: A0[0,16K) A1[16K,32K) B0[32K,48K) B1[48K,64K)
//   region = 128 rows x 64 k bf16, row stride 128B, k stored as 8x16B granules,
//   slot s of row r holds global granule s ^ (r&7)  (bank-balanced XOR swizzle).
// Phases per K-tile i (quadrants of per-wave 128x64 output):
//   p0: ldA(m0)+ldB(n0) | stage A0(i+1) | bar | mfma(m0,n0) | bar
//   p1: ldB(n1)         | stage A1(i+1) | bar | mfma(m0,n1) | bar
//   p2: ldA(m1)         | stage B0(i+2) | bar | mfma(m1,n0) | bar
//   p3:                 | stage B1(i+2) | vmcnt(4) | bar | mfma(m1,n1) | bar
// Race-safety: A(i+1) writes other dbuf; B(i+2) writes regions whose reads
// drained before p1's 2nd barrier; vmcnt(4)@p3 -> tile i+1 landed before its p0.
// =====================================================================

#define BAR { __builtin_amdgcn_s_barrier(); asm volatile("" ::: "memory"); }
#define VMC4 asm volatile("s_waitcnt vmcnt(4)" ::: "memory")
#define VMC0 asm volatile("s_waitcnt vmcnt(0)" ::: "memory")

#define LDA(msub) { \
  const char* Ab = sm + dbuf + wr * 16384; \
  _Pragma("unroll") for (int m = 0; m < 4; m++) { \
    int row = ((msub) * 4 + m) * 16 + lr; \
    af[m][0] = *(const bf16x8*)(Ab + row * 128 + xk0); \
    af[m][1] = *(const bf16x8*)(Ab + row * 128 + xk1); \
  } }

#define LDB(nsub) { \
  const char* Bb = sm + dbuf + 32768 + (wc >> 1) * 16384; \
  _Pragma("unroll") for (int n = 0; n < 2; n++) { \
    int row = (wc & 1) * 64 + ((nsub) * 2 + n) * 16 + lr; \
    bfr[(nsub)*2+n][0] = *(const bf16x8*)(Bb + row * 128 + xk0); \
    bfr[(nsub)*2+n][1] = *(const bf16x8*)(Bb + row * 128 + xk1); \
  } }

#define MFMA_Q(msub, nsub) { \
  __builtin_amdgcn_s_setprio(1); \
  _Pragma("unroll") for (int m = 0; m < 4; m++) \
  _Pragma("unroll") for (int n = 0; n < 2; n++) \
  _Pragma("unroll") for (int k = 0; k < 2; k++) \
    acc[(msub)*4+m][(nsub)*2+n] = __builtin_amdgcn_mfma_f32_16x16x32_bf16( \
        af[m][k], bfr[(nsub)*2+n][k], acc[(msub)*4+m][(nsub)*2+n], 0, 0, 0); \
  __builtin_amdgcn_s_setprio(0); }

#define DO_TILE(i, S0, S1, S2, S3, VW) { \
  const int dbuf = ((i) & 1) * 65536; \
  LDA(0); LDB(0); S0; BAR; MFMA_Q(0,0); BAR; \
  LDB(1);         S1; BAR; MFMA_Q(0,1); BAR; \
  LDA(1);         S2; BAR; MFMA_Q(1,0); BAR; \
                  S3; VW; BAR; MFMA_Q(1,1); BAR; \
}

__launch_bounds__(512, 2)
__global__ void k_gemm1(const bf16* __restrict__ xb, const bf16* __restrict__ wte,
                        const float* __restrict__ b_e, bf16* __restrict__ hb,
                        const int* __restrict__ meta) {
    __shared__ __align__(16) char sm[2 * 65536];
    int nt = meta[25];
    int tileIdx = blockIdx.y;
    if (tileIdx >= nt) return;
    int e  = meta[32 + tileIdx];
    int rs = meta[128 + tileIdx];
    int rc = meta[256 + tileIdx];
    const int* perm = meta + 512;
    int n0 = blockIdx.x * 256;

    int tid = threadIdx.x;
    int lane = tid & 63, wid = tid >> 6;
    int wr = wid >> 2, wc = wid & 3;
    int lr = lane & 15, kg = lane >> 4;
    int xk0 = (kg ^ (lr & 7)) * 16;
    int xk1 = ((4 + kg) ^ (lr & 7)) * 16;

    // staging: thread covers (region row r*64 + sr, slot sl); global granule g
    int sr = tid >> 3, sl = tid & 7;
    int g = sl ^ (sr & 7);
    const bf16* pa[2][2];
#pragma unroll
    for (int h = 0; h < 2; h++)
#pragma unroll
      for (int r = 0; r < 2; r++) {
        int arow = h * 128 + r * 64 + sr;
        int tok = perm[rs + (arow < rc - 1 ? arow : rc - 1)];
        pa[h][r] = xb + (size_t)tok * ND + g * 8;
      }
    const bf16* pb0 = wte + ((size_t)e * NH + n0 + sr) * ND + g * 8;

#define STAGE_A(t, h) { \
    char* d = sm + ((t) & 1) * 65536 + (h) * 16384 + wid * 1024; \
    GLDS16(pa[h][0] + (size_t)(t) * 64, d); \
    GLDS16(pa[h][1] + (size_t)(t) * 64, d + 8192); }
#define STAGE_B(t, h) { \
    char* d = sm + ((t) & 1) * 65536 + 32768 + (h) * 16384 + wid * 1024; \
    GLDS16(pb0 + ((h) * 128) * (size_t)ND + (size_t)(t) * 64, d); \
    GLDS16(pb0 + ((h) * 128 + 64) * (size_t)ND + (size_t)(t) * 64, d + 8192); }

    f32x4 acc[8][4] = {};
    bf16x8 af[4][2], bfr[4][2];
    const int NT = ND / 64;   // 16

    // prologue: tile0 fully + tile1 B halves; wait tile0
    STAGE_B(0, 0); STAGE_B(0, 1); STAGE_A(0, 0); STAGE_A(0, 1);
    STAGE_B(1, 0); STAGE_B(1, 1);
    VMC4;
    BAR;

#pragma unroll 2
    for (int i = 0; i < NT - 2; i++)
        DO_TILE(i, STAGE_A(i + 1, 0), STAGE_A(i + 1, 1),
                   STAGE_B(i + 2, 0), STAGE_B(i + 2, 1), VMC4);
    DO_TILE(NT - 2, STAGE_A(NT - 1, 0), STAGE_A(NT - 1, 1), , , VMC0);
    DO_TILE(NT - 1, , , , , );

    // epilogue: bias + relu, bf16, permuted (dense) row order
    float bias[4];
#pragma unroll
    for (int n = 0; n < 4; n++) bias[n] = b_e[e * NH + n0 + wc * 64 + n * 16 + lr];
#pragma unroll
    for (int m = 0; m < 8; m++) {
#pragma unroll
        for (int r = 0; r < 4; r++) {
            int row = wr * 128 + m * 16 + kg * 4 + r;
            if (row < rc) {
                bf16* hp = hb + (size_t)(rs + row) * NH + n0 + wc * 64;
#pragma unroll
                for (int n = 0; n < 4; n++)
                    hp[n * 16 + lr] = (bf16)fmaxf(acc[m][n][r] + bias[n], 0.0f);
            }
        }
    }
#undef STAGE_A
#undef STAGE_B
}

__launch_bounds__(512, 2)
__global__ void k_gemm2(const bf16* __restrict__ hb, const bf16* __restrict__ wto,
                        const float* __restrict__ b_out, const int* __restrict__ meta,
                        float* __restrict__ out) {
    __shared__ __align__(16) char sm[2 * 65536];
    // XCD-aware swizzle over exactly 256 blocks
    int lin = blockIdx.x;
    int swz = (lin & 7) * 32 + (lin >> 3);
    int bx = swz & 3, by = swz >> 2;
    int m0 = by * 256, n0 = bx * 256;
    const int* perm = meta + 512;

    int tid = threadIdx.x;
    int lane = tid & 63, wid = tid >> 6;
    int wr = wid >> 2, wc = wid & 3;
    int lr = lane & 15, kg = lane >> 4;
    int xk0 = (kg ^ (lr & 7)) * 16;
    int xk1 = ((4 + kg) ^ (lr & 7)) * 16;

    int sr = tid >> 3, sl = tid & 7;
    int g = sl ^ (sr & 7);
    const bf16* pa0 = hb  + ((size_t)m0 + sr) * NH + g * 8;
    const bf16* pb0 = wto + ((size_t)n0 + sr) * NH + g * 8;

#define STAGE_A(t, h) { \
    char* d = sm + ((t) & 1) * 65536 + (h) * 16384 + wid * 1024; \
    GLDS16(pa0 + ((h) * 128) * (size_t)NH + (size_t)(t) * 64, d); \
    GLDS16(pa0 + ((h) * 128 + 64) * (size_t)NH + (size_t)(t) * 64, d + 8192); }
#define STAGE_B(t, h) { \
    char* d = sm + ((t) & 1) * 65536 + 32768 + (h) * 16384 + wid * 1024; \
    GLDS16(pb0 + ((h) * 128) * (size_t)NH + (size_t)(t) * 64, d); \
    GLDS16(pb0 + ((h) * 128 + 64) * (size_t)NH + (size_t)(t) * 64, d + 8192); }

    f32x4 acc[8][4] = {};
    bf16x8 af[4][2], bfr[4][2];
    const int NT = NH / 64;   // 64

    STAGE_B(0, 0); STAGE_B(0, 1); STAGE_A(0, 0); STAGE_A(0, 1);
    STAGE_B(1, 0); STAGE_B(1, 1);
    VMC4;
    BAR;

#pragma unroll 2
    for (int i = 0; i < NT - 2; i++)
        DO_TILE(i, STAGE_A(i + 1, 0), STAGE_A(i + 1, 1),
                   STAGE_B(i + 2, 0), STAGE_B(i + 2, 1), VMC4);
    DO_TILE(NT - 2, STAGE_A(NT - 1, 0), STAGE_A(NT - 1, 1), , , VMC0);
    DO_TILE(NT - 1, , , , , );

    // epilogue: bias, scatter rows to token order via perm
    float bias[4];
#pragma unroll
    for (int n = 0; n < 4; n++) bias[n] = b_out[n0 + wc * 64 + n * 16 + lr];
#pragma unroll
    for (int m = 0; m < 8; m++) {
#pragma unroll
        for (int r = 0; r < 4; r++) {
            int prow = m0 + wr * 128 + m * 16 + kg * 4 + r;
            int tok = perm[prow];
            float* op = out + (size_t)tok * ND + n0 + wc * 64;
#pragma unroll
            for (int n = 0; n < 4; n++)
                op[n * 16 + lr] = acc[m][n][r] + bias[n];
        }
    }
#undef STAGE_A
#undef STAGE_B
}

extern "C" void kernel_launch(void* const* d_in, const int* in_sizes, int n_in,
                              void* d_out, int out_size, void* d_ws, size_t ws_size,
                              hipStream_t stream) {
    const float* x     = (const float*)d_in[0];
    const float* W_e   = (const float*)d_in[1];
    const float* b_e   = (const float*)d_in[2];
    const float* W_out = (const float*)d_in[3];
    const float* b_out = (const float*)d_in[4];
    const int*   assign = (const int*)d_in[5];
    float* out = (float*)d_out;

    if (ws_size < WS_NEED) return;

    char* ws = (char*)d_ws;
    int*  meta = (int*)ws;
    bf16* xb  = (bf16*)(ws + OFF_XB);
    bf16* wte = (bf16*)(ws + OFF_WTE);
    bf16* wto = (bf16*)(ws + OFF_WTO);
    bf16* hb  = (bf16*)(ws + OFF_HB);

    hipMemsetAsync(meta, 0, 512 * sizeof(int), stream);

    k_cvt_x<<<NTOK * ND / (256 * 8), 256, 0, stream>>>(x, xb);
    k_hist<<<NTOK / 256, 256, 0, stream>>>(assign, meta);
    k_desc<<<1, 64, 0, stream>>>(meta);
    k_scatter<<<NTOK / 256, 256, 0, stream>>>(assign, meta);
    k_transpose<<<dim3(NH / 32, ND / 32, NE), dim3(32, 8), 0, stream>>>(W_e, wte, ND, NH);
    k_transpose<<<dim3(ND / 32, NH / 32, 1), dim3(32, 8), 0, stream>>>(W_out, wto, NH, ND);
    // grouped GEMM1: max tiles = 16384/256 + 8 = 72
    k_gemm1<<<dim3(NH / 256, 72), 512, 0, stream>>>(xb, wte, b_e, hb, meta);
    // dense GEMM2 over permuted hb rows, scatter at the end
    k_gemm2<<<256, 512, 0, stream>>>(hb, wto, b_out, meta, out);
}

// Round 4
// 490.860 us; speedup vs baseline: 1.3999x; 1.0043x over previous
//
#include <hip/hip_runtime.h>
#include <hip/hip_bf16.h>
#include <stdint.h>

// Problem dims (fixed)
#define NB 8
#define NS 2048
#define ND 1024
#define NH 4096
#define NE 8
#define NTOK (NB*NS)   // 16384 tokens

typedef __bf16 bf16;
typedef bf16 bf16x8 __attribute__((ext_vector_type(8)));
typedef float f32x4 __attribute__((ext_vector_type(4)));

// ws layout: meta[512] ints + perm[16384] at meta+512, then:
static const size_t OFF_XB  = 128 * 1024;                          // bf16 xbp[NTOK][ND]  (PERMUTED rows)
static const size_t OFF_WTE = OFF_XB  + (size_t)NTOK * ND * 2;     // bf16 wte[NE][NH][ND]
static const size_t OFF_WTO = OFF_WTE + (size_t)NE * NH * ND * 2;  // bf16 wto[ND][NH]
static const size_t OFF_HB  = OFF_WTO + (size_t)ND * NH * 2;       // bf16 hb [NTOK][NH] (permuted rows)
static const size_t WS_NEED = OFF_HB  + (size_t)NTOK * NH * 2;

#define GLDS16(src, dst) __builtin_amdgcn_global_load_lds( \
    (__attribute__((address_space(1))) void*)(void*)(src), \
    (__attribute__((address_space(3))) void*)(dst), 16, 0, 0)

// ---------------- prep kernels ----------------

__global__ void k_hist(const int* __restrict__ assign, int* __restrict__ meta) {
    int t = blockIdx.x * blockDim.x + threadIdx.x;
    if (t < NTOK) atomicAdd(&meta[assign[t] & 7], 1);
}

// 64-lane parallel descriptor build (registers, minimal global round-trips)
__global__ void k_desc(int* __restrict__ meta) {
    int lane = threadIdx.x;
    int counts[NE], offs[NE + 1];
    offs[0] = 0;
#pragma unroll
    for (int e = 0; e < NE; e++) { counts[e] = meta[e]; offs[e + 1] = offs[e] + counts[e]; }
    if (lane < NE + 1) meta[16 + lane] = offs[lane];
    int base[NE];
    int nt = 0;
#pragma unroll
    for (int e = 0; e < NE; e++) { base[e] = nt; nt += (counts[e] + 255) >> 8; }
    if (lane == 0) meta[25] = nt;
    for (int t = lane; t < nt; t += 64) {
        int e = 0;
#pragma unroll
        for (int k = 1; k < NE; k++) if (t >= base[k]) e = k;
        int t0 = (t - base[e]) << 8;
        meta[32 + t] = e;
        meta[128 + t] = offs[e] + t0;
        meta[256 + t] = min(256, counts[e] - t0);
    }
}

__global__ void k_scatter(const int* __restrict__ assign, int* __restrict__ meta) {
    int t = blockIdx.x * blockDim.x + threadIdx.x;
    if (t < NTOK) {
        int e = assign[t] & 7;
        int p = atomicAdd(&meta[8 + e], 1);
        int* perm = meta + 512;
        perm[meta[16 + e] + p] = t;
    }
}

// gather + f32->bf16: xbp[p][:] = bf16(x[perm[p]][:])
__global__ void k_gather_cvt(const float* __restrict__ x, const int* __restrict__ meta,
                             bf16* __restrict__ xbp) {
    long i = (long)blockIdx.x * blockDim.x + threadIdx.x;   // 8 elems each
    int row = (int)(i >> 7);      // ND/8 = 128 chunks per row
    int c8  = (int)(i & 127);
    const int* perm = meta + 512;
    int tok = perm[row];
    const float4* s = (const float4*)(x + (size_t)tok * ND + c8 * 8);
    float4 v0 = s[0], v1 = s[1];
    bf16x8 o;
    o[0] = (bf16)v0.x; o[1] = (bf16)v0.y; o[2] = (bf16)v0.z; o[3] = (bf16)v0.w;
    o[4] = (bf16)v1.x; o[5] = (bf16)v1.y; o[6] = (bf16)v1.z; o[7] = (bf16)v1.w;
    *(bf16x8*)(xbp + i * 8) = o;
}

// transpose+convert: in [batch][R][C] f32 -> out [batch][C][R] bf16
__global__ void k_transpose(const float* __restrict__ in, bf16* __restrict__ out,
                            int R, int C) {
    __shared__ float tile[32][33];
    int b  = blockIdx.z;
    int c0 = blockIdx.x * 32, r0 = blockIdx.y * 32;
    const float* inb = in + (size_t)b * R * C;
    bf16* outb = out + (size_t)b * R * C;
    int tx = threadIdx.x, ty = threadIdx.y;
#pragma unroll
    for (int i = 0; i < 4; i++) {
        int r = r0 + ty + i * 8;
        tile[ty + i * 8][tx] = inb[(size_t)r * C + c0 + tx];
    }
    __syncthreads();
#pragma unroll
    for (int i = 0; i < 4; i++) {
        int c = c0 + ty + i * 8;
        outb[(size_t)c * R + r0 + tx] = (bf16)tile[tx][ty + i * 8];
    }
}

// =====================================================================
// 8-phase 256x256 GEMM template, BK=64, 8 waves (2Mx4N).  See R3 notes.
// LDS: 2 dbuf x 64KB; per dbuf: A0[0,16K) A1[16K,32K) B0[32K,48K) B1[48K,64K)
//   region = 128 rows x 64 k bf16; slot s of row r holds granule s ^ (r&7).
// =====================================================================

#define BAR { __builtin_amdgcn_s_barrier(); asm volatile("" ::: "memory"); }
#define VMC4 asm volatile("s_waitcnt vmcnt(4)" ::: "memory")
#define VMC0 asm volatile("s_waitcnt vmcnt(0)" ::: "memory")

#define LDA(msub) { \
  const char* Ab = sm + dbuf + wr * 16384; \
  _Pragma("unroll") for (int m = 0; m < 4; m++) { \
    int row = ((msub) * 4 + m) * 16 + lr; \
    af[m][0] = *(const bf16x8*)(Ab + row * 128 + xk0); \
    af[m][1] = *(const bf16x8*)(Ab + row * 128 + xk1); \
  } }

#define LDB(nsub) { \
  const char* Bb = sm + dbuf + 32768 + (wc >> 1) * 16384; \
  _Pragma("unroll") for (int n = 0; n < 2; n++) { \
    int row = (wc & 1) * 64 + ((nsub) * 2 + n) * 16 + lr; \
    bfr[(nsub)*2+n][0] = *(const bf16x8*)(Bb + row * 128 + xk0); \
    bfr[(nsub)*2+n][1] = *(const bf16x8*)(Bb + row * 128 + xk1); \
  } }

#define MFMA_Q(msub, nsub) { \
  __builtin_amdgcn_s_setprio(1); \
  _Pragma("unroll") for (int m = 0; m < 4; m++) \
  _Pragma("unroll") for (int n = 0; n < 2; n++) \
  _Pragma("unroll") for (int k = 0; k < 2; k++) \
    acc[(msub)*4+m][(nsub)*2+n] = __builtin_amdgcn_mfma_f32_16x16x32_bf16( \
        af[m][k], bfr[(nsub)*2+n][k], acc[(msub)*4+m][(nsub)*2+n], 0, 0, 0); \
  __builtin_amdgcn_s_setprio(0); }

#define DO_TILE(i, S0, S1, S2, S3, VW) { \
  const int dbuf = ((i) & 1) * 65536; \
  LDA(0); LDB(0); S0; BAR; MFMA_Q(0,0); BAR; \
  LDB(1);         S1; BAR; MFMA_Q(0,1); BAR; \
  LDA(1);         S2; BAR; MFMA_Q(1,0); BAR; \
                  S3; VW; BAR; MFMA_Q(1,1); BAR; \
}

__launch_bounds__(512, 2)
__global__ void k_gemm1(const bf16* __restrict__ xbp, const bf16* __restrict__ wte,
                        const float* __restrict__ b_e, bf16* __restrict__ hb,
                        const int* __restrict__ meta) {
    __shared__ __align__(16) char sm[2 * 65536];
    int nt = meta[25];
    // XCD-chunked decode: all 16 n-blocks of one tile land on one XCD
    int f = blockIdx.x;
    int xcd = f & 7, j = f >> 3;
    int bx = j & 15, tslot = j >> 4;          // 16 bx x 9 tslots x 8 xcd = 1152
    int tileIdx = xcd + 8 * tslot;            // 0..71
    if (tileIdx >= nt) return;
    int e  = meta[32 + tileIdx];
    int rs = meta[128 + tileIdx];
    int rc = meta[256 + tileIdx];
    int n0 = bx * 256;

    int tid = threadIdx.x;
    int lane = tid & 63, wid = tid >> 6;
    int wr = wid >> 2, wc = wid & 3;
    int lr = lane & 15, kg = lane >> 4;
    int xk0 = (kg ^ (lr & 7)) * 16;
    int xk1 = ((4 + kg) ^ (lr & 7)) * 16;

    // staging: thread covers (region row, slot sl); global granule g
    int sr = tid >> 3, sl = tid & 7;
    int g = sl ^ (sr & 7);
    const bf16* pa[2][2];
#pragma unroll
    for (int h = 0; h < 2; h++)
#pragma unroll
      for (int r = 0; r < 2; r++) {
        int arow = h * 128 + r * 64 + sr;
        int p = rs + (arow < rc - 1 ? arow : rc - 1);
        pa[h][r] = xbp + (size_t)p * ND + g * 8;
      }
    const bf16* pb0 = wte + ((size_t)e * NH + n0 + sr) * ND + g * 8;

#define STAGE_A(t, h) { \
    char* d = sm + ((t) & 1) * 65536 + (h) * 16384 + wid * 1024; \
    GLDS16(pa[h][0] + (size_t)(t) * 64, d); \
    GLDS16(pa[h][1] + (size_t)(t) * 64, d + 8192); }
#define STAGE_B(t, h) { \
    char* d = sm + ((t) & 1) * 65536 + 32768 + (h) * 16384 + wid * 1024; \
    GLDS16(pb0 + ((h) * 128) * (size_t)ND + (size_t)(t) * 64, d); \
    GLDS16(pb0 + ((h) * 128 + 64) * (size_t)ND + (size_t)(t) * 64, d + 8192); }

    f32x4 acc[8][4] = {};
    bf16x8 af[4][2], bfr[4][2];
    const int NT = ND / 64;   // 16

    STAGE_B(0, 0); STAGE_B(0, 1); STAGE_A(0, 0); STAGE_A(0, 1);
    STAGE_B(1, 0); STAGE_B(1, 1);
    VMC4;
    BAR;

#pragma unroll 2
    for (int i = 0; i < NT - 2; i++)
        DO_TILE(i, STAGE_A(i + 1, 0), STAGE_A(i + 1, 1),
                   STAGE_B(i + 2, 0), STAGE_B(i + 2, 1), VMC4);
    DO_TILE(NT - 2, STAGE_A(NT - 1, 0), STAGE_A(NT - 1, 1), , , VMC0);
    DO_TILE(NT - 1, , , , , );

    // epilogue: bias + relu, bf16, permuted (dense) row order
    float bias[4];
#pragma unroll
    for (int n = 0; n < 4; n++) bias[n] = b_e[e * NH + n0 + wc * 64 + n * 16 + lr];
#pragma unroll
    for (int m = 0; m < 8; m++) {
#pragma unroll
        for (int r = 0; r < 4; r++) {
            int row = wr * 128 + m * 16 + kg * 4 + r;
            if (row < rc) {
                bf16* hp = hb + (size_t)(rs + row) * NH + n0 + wc * 64;
#pragma unroll
                for (int n = 0; n < 4; n++)
                    hp[n * 16 + lr] = (bf16)fmaxf(acc[m][n][r] + bias[n], 0.0f);
            }
        }
    }
#undef STAGE_A
#undef STAGE_B
}

__launch_bounds__(512, 2)
__global__ void k_gemm2(const bf16* __restrict__ hb, const bf16* __restrict__ wto,
                        const float* __restrict__ b_out, const int* __restrict__ meta,
                        float* __restrict__ out) {
    __shared__ __align__(16) char sm[2 * 65536];
    // XCD-aware swizzle over exactly 256 blocks (32 consecutive per XCD)
    int lin = blockIdx.x;
    int swz = (lin & 7) * 32 + (lin >> 3);
    int bx = swz & 3, by = swz >> 2;
    int m0 = by * 256, n0 = bx * 256;
    const int* perm = meta + 512;

    int tid = threadIdx.x;
    int lane = tid & 63, wid = tid >> 6;
    int wr = wid >> 2, wc = wid & 3;
    int lr = lane & 15, kg = lane >> 4;
    int xk0 = (kg ^ (lr & 7)) * 16;
    int xk1 = ((4 + kg) ^ (lr & 7)) * 16;

    int sr = tid >> 3, sl = tid & 7;
    int g = sl ^ (sr & 7);
    const bf16* pa0 = hb  + ((size_t)m0 + sr) * NH + g * 8;
    const bf16* pb0 = wto + ((size_t)n0 + sr) * NH + g * 8;

#define STAGE_A(t, h) { \
    char* d = sm + ((t) & 1) * 65536 + (h) * 16384 + wid * 1024; \
    GLDS16(pa0 + ((h) * 128) * (size_t)NH + (size_t)(t) * 64, d); \
    GLDS16(pa0 + ((h) * 128 + 64) * (size_t)NH + (size_t)(t) * 64, d + 8192); }
#define STAGE_B(t, h) { \
    char* d = sm + ((t) & 1) * 65536 + 32768 + (h) * 16384 + wid * 1024; \
    GLDS16(pb0 + ((h) * 128) * (size_t)NH + (size_t)(t) * 64, d); \
    GLDS16(pb0 + ((h) * 128 + 64) * (size_t)NH + (size_t)(t) * 64, d + 8192); }

    f32x4 acc[8][4] = {};
    bf16x8 af[4][2], bfr[4][2];
    const int NT = NH / 64;   // 64

    STAGE_B(0, 0); STAGE_B(0, 1); STAGE_A(0, 0); STAGE_A(0, 1);
    STAGE_B(1, 0); STAGE_B(1, 1);
    VMC4;
    BAR;

#pragma unroll 2
    for (int i = 0; i < NT - 2; i++)
        DO_TILE(i, STAGE_A(i + 1, 0), STAGE_A(i + 1, 1),
                   STAGE_B(i + 2, 0), STAGE_B(i + 2, 1), VMC4);
    DO_TILE(NT - 2, STAGE_A(NT - 1, 0), STAGE_A(NT - 1, 1), , , VMC0);
    DO_TILE(NT - 1, , , , , );

    // epilogue: bias, scatter rows to token order via perm
    float bias[4];
#pragma unroll
    for (int n = 0; n < 4; n++) bias[n] = b_out[n0 + wc * 64 + n * 16 + lr];
#pragma unroll
    for (int m = 0; m < 8; m++) {
#pragma unroll
        for (int r = 0; r < 4; r++) {
            int prow = m0 + wr * 128 + m * 16 + kg * 4 + r;
            int tok = perm[prow];
            float* op = out + (size_t)tok * ND + n0 + wc * 64;
#pragma unroll
            for (int n = 0; n < 4; n++)
                op[n * 16 + lr] = acc[m][n][r] + bias[n];
        }
    }
#undef STAGE_A
#undef STAGE_B
}

extern "C" void kernel_launch(void* const* d_in, const int* in_sizes, int n_in,
                              void* d_out, int out_size, void* d_ws, size_t ws_size,
                              hipStream_t stream) {
    const float* x     = (const float*)d_in[0];
    const float* W_e   = (const float*)d_in[1];
    const float* b_e   = (const float*)d_in[2];
    const float* W_out = (const float*)d_in[3];
    const float* b_out = (const float*)d_in[4];
    const int*   assign = (const int*)d_in[5];
    float* out = (float*)d_out;

    if (ws_size < WS_NEED) return;

    char* ws = (char*)d_ws;
    int*  meta = (int*)ws;
    bf16* xbp = (bf16*)(ws + OFF_XB);
    bf16* wte = (bf16*)(ws + OFF_WTE);
    bf16* wto = (bf16*)(ws + OFF_WTO);
    bf16* hb  = (bf16*)(ws + OFF_HB);

    hipMemsetAsync(meta, 0, 512 * sizeof(int), stream);

    // routing first (gather_cvt depends on perm)
    k_hist<<<NTOK / 256, 256, 0, stream>>>(assign, meta);
    k_desc<<<1, 64, 0, stream>>>(meta);
    k_scatter<<<NTOK / 256, 256, 0, stream>>>(assign, meta);
    k_gather_cvt<<<NTOK * ND / (256 * 8), 256, 0, stream>>>(x, meta, xbp);
    k_transpose<<<dim3(NH / 32, ND / 32, NE), dim3(32, 8), 0, stream>>>(W_e, wte, ND, NH);
    k_transpose<<<dim3(ND / 32, NH / 32, 1), dim3(32, 8), 0, stream>>>(W_out, wto, NH, ND);
    // grouped GEMM1: 1-D grid, XCD-chunked (16 bx x 9 tslots x 8 xcd)
    k_gemm1<<<1152, 512, 0, stream>>>(xbp, wte, b_e, hb, meta);
    // dense GEMM2 over permuted hb rows, scatter at the end
    k_gemm2<<<256, 512, 0, stream>>>(hb, wto, b_out, meta, out);
}

// Round 5
// 443.136 us; speedup vs baseline: 1.5506x; 1.1077x over previous
//
#include <hip/hip_runtime.h>
#include <hip/hip_bf16.h>
#include <stdint.h>

// Problem dims (fixed)
#define NB 8
#define NS 2048
#define ND 1024
#define NH 4096
#define NE 8
#define NTOK (NB*NS)   // 16384 tokens

typedef __bf16 bf16;
typedef bf16 bf16x8 __attribute__((ext_vector_type(8)));
typedef float f32x4 __attribute__((ext_vector_type(4)));

// ws layout: meta[512] ints + perm[16384] at meta+512, then:
static const size_t OFF_XB  = 128 * 1024;                          // bf16 xbp[NTOK][ND]  (PERMUTED rows)
static const size_t OFF_WTE = OFF_XB  + (size_t)NTOK * ND * 2;     // bf16 wte[NE][NH][ND]
static const size_t OFF_WTO = OFF_WTE + (size_t)NE * NH * ND * 2;  // bf16 wto[ND][NH]
static const size_t OFF_HB  = OFF_WTO + (size_t)ND * NH * 2;       // bf16 hb [NTOK][NH] (permuted rows)
static const size_t WS_NEED = OFF_HB  + (size_t)NTOK * NH * 2;

#define GLDS16(src, dst) __builtin_amdgcn_global_load_lds( \
    (__attribute__((address_space(1))) void*)(void*)(src), \
    (__attribute__((address_space(3))) void*)(dst), 16, 0, 0)

// ---------------- prep kernels ----------------

// fused routing: histogram + prefix + scatter, ONE block (1024 thr)
__global__ void k_route(const int* __restrict__ assign, int* __restrict__ meta) {
    __shared__ int cnt[NE];
    __shared__ int offs_s[NE];
    int tid = threadIdx.x;
    if (tid < NE) cnt[tid] = 0;
    __syncthreads();
    for (int t = tid; t < NTOK; t += 1024) atomicAdd(&cnt[assign[t] & 7], 1);
    __syncthreads();
    if (tid == 0) {
        int o = 0;
        for (int e = 0; e < NE; e++) {
            meta[e] = cnt[e]; meta[16 + e] = o; offs_s[e] = o; o += cnt[e];
        }
    }
    __syncthreads();
    if (tid < NE) cnt[tid] = offs_s[tid];   // reuse as cursors
    __syncthreads();
    int* perm = meta + 512;
    for (int t = tid; t < NTOK; t += 1024) {
        int e = assign[t] & 7;
        int p = atomicAdd(&cnt[e], 1);
        perm[p] = t;
    }
}

// gather + f32->bf16: xbp[p][:] = bf16(x[perm[p]][:])
__global__ void k_gather_cvt(const float* __restrict__ x, const int* __restrict__ meta,
                             bf16* __restrict__ xbp) {
    long i = (long)blockIdx.x * blockDim.x + threadIdx.x;   // 8 elems each
    int row = (int)(i >> 7);      // ND/8 = 128 chunks per row
    int c8  = (int)(i & 127);
    const int* perm = meta + 512;
    int tok = perm[row];
    const float4* s = (const float4*)(x + (size_t)tok * ND + c8 * 8);
    float4 v0 = s[0], v1 = s[1];
    bf16x8 o;
    o[0] = (bf16)v0.x; o[1] = (bf16)v0.y; o[2] = (bf16)v0.z; o[3] = (bf16)v0.w;
    o[4] = (bf16)v1.x; o[5] = (bf16)v1.y; o[6] = (bf16)v1.z; o[7] = (bf16)v1.w;
    *(bf16x8*)(xbp + i * 8) = o;
}

// transpose+convert: in [batch][R][C] f32 -> out [batch][C][R] bf16
__global__ void k_transpose(const float* __restrict__ in, bf16* __restrict__ out,
                            int R, int C) {
    __shared__ float tile[32][33];
    int b  = blockIdx.z;
    int c0 = blockIdx.x * 32, r0 = blockIdx.y * 32;
    const float* inb = in + (size_t)b * R * C;
    bf16* outb = out + (size_t)b * R * C;
    int tx = threadIdx.x, ty = threadIdx.y;
#pragma unroll
    for (int i = 0; i < 4; i++) {
        int r = r0 + ty + i * 8;
        tile[ty + i * 8][tx] = inb[(size_t)r * C + c0 + tx];
    }
    __syncthreads();
#pragma unroll
    for (int i = 0; i < 4; i++) {
        int c = c0 + ty + i * 8;
        outb[(size_t)c * R + r0 + tx] = (bf16)tile[tx][ty + i * 8];
    }
}

// =====================================================================
// 8-phase 256x256 GEMM, BK=64, 8 waves (2Mx4N), DEEP pipeline:
//  A: 3-deep buffers (staged at distance i+2, 7-phase prefetch window)
//  B: 2-deep buffers (staged at distance i+2, written after reads drain)
//  vmcnt(8): 8 loads in flight (A(i+2)x4 + B(i+2)x4), wait covers tile i+1.
// LDS 160KB: A bufs [0,96K) = 3 x (h0 16K | h1 16K); B bufs [96K,160K) = 2 x 32K.
// Region = 128 rows x 64 k bf16, row stride 128B; slot s of row r holds
// global granule s ^ (r&7)  (bank-balanced XOR swizzle, conflict-free).
// =====================================================================

#define BAR { __builtin_amdgcn_s_barrier(); asm volatile("" ::: "memory"); }
#define VMC8 asm volatile("s_waitcnt vmcnt(8)" ::: "memory")
#define VMC0 asm volatile("s_waitcnt vmcnt(0)" ::: "memory")

#define LDA(msub) { \
  const char* Ab = sm + abuf + wr * 16384; \
  _Pragma("unroll") for (int m = 0; m < 4; m++) { \
    int row = ((msub) * 4 + m) * 16 + lr; \
    af[m][0] = *(const bf16x8*)(Ab + row * 128 + xk0); \
    af[m][1] = *(const bf16x8*)(Ab + row * 128 + xk1); \
  } }

#define LDB(nsub) { \
  const char* Bb = sm + bbuf + (wc >> 1) * 16384; \
  _Pragma("unroll") for (int n = 0; n < 2; n++) { \
    int row = (wc & 1) * 64 + ((nsub) * 2 + n) * 16 + lr; \
    bfr[(nsub)*2+n][0] = *(const bf16x8*)(Bb + row * 128 + xk0); \
    bfr[(nsub)*2+n][1] = *(const bf16x8*)(Bb + row * 128 + xk1); \
  } }

#define MFMA_Q(msub, nsub) { \
  __builtin_amdgcn_s_setprio(1); \
  _Pragma("unroll") for (int m = 0; m < 4; m++) \
  _Pragma("unroll") for (int n = 0; n < 2; n++) \
  _Pragma("unroll") for (int k = 0; k < 2; k++) \
    acc[(msub)*4+m][(nsub)*2+n] = __builtin_amdgcn_mfma_f32_16x16x32_bf16( \
        af[m][k], bfr[(nsub)*2+n][k], acc[(msub)*4+m][(nsub)*2+n], 0, 0, 0); \
  __builtin_amdgcn_s_setprio(0); }

#define DO_TILE(i, S0, S1, S2, S3, VW) { \
  const int abuf = ((i) % 3) * 32768; \
  const int bbuf = 98304 + ((i) & 1) * 32768; \
  LDA(0); LDB(0); S0; BAR; MFMA_Q(0,0); BAR; \
  LDB(1);         S1; BAR; MFMA_Q(0,1); BAR; \
  LDA(1);         S2; BAR; MFMA_Q(1,0); BAR; \
                  S3; VW; BAR; MFMA_Q(1,1); BAR; \
}

// STAGE macros (shared by both gemms; define pa/pb pointers first)
#define STAGE_A(t, h) { \
    char* d = sm + ((t) % 3) * 32768 + (h) * 16384 + wid * 1024; \
    GLDS16(srcA(t, h, 0), d); \
    GLDS16(srcA(t, h, 1), d + 8192); }
#define STAGE_B(t, h) { \
    char* d = sm + 98304 + ((t) & 1) * 32768 + (h) * 16384 + wid * 1024; \
    GLDS16(srcB(t, h, 0), d); \
    GLDS16(srcB(t, h, 1), d + 8192); }

__launch_bounds__(512, 2)
__global__ void k_gemm1(const bf16* __restrict__ xbp, const bf16* __restrict__ wte,
                        const float* __restrict__ b_e, bf16* __restrict__ hb,
                        const int* __restrict__ meta) {
    __shared__ __align__(16) char sm[163840];
    // fixed 9 tiles/expert; expert == XCD (bid & 7) for full weight locality
    int f = blockIdx.x;
    int e = f & 7, r2 = f >> 3;
    int bx = r2 & 15, j = r2 >> 4;           // j = 0..8
    int cnt = meta[e];
    int rs  = meta[16 + e] + j * 256;
    int rc  = cnt - j * 256; if (rc > 256) rc = 256;
    if (rc <= 0) return;
    int n0 = bx * 256;

    int tid = threadIdx.x;
    int lane = tid & 63, wid = tid >> 6;
    int wr = wid >> 2, wc = wid & 3;
    int lr = lane & 15, kg = lane >> 4;
    int xk0 = (kg ^ (lr & 7)) * 16;
    int xk1 = ((4 + kg) ^ (lr & 7)) * 16;

    int sr = tid >> 3, sl = tid & 7;
    int g = sl ^ (sr & 7);
    const bf16* pa[2][2];
#pragma unroll
    for (int h = 0; h < 2; h++)
#pragma unroll
      for (int rr = 0; rr < 2; rr++) {
        int arow = h * 128 + rr * 64 + sr;
        int p = rs + (arow < rc - 1 ? arow : rc - 1);
        pa[h][rr] = xbp + (size_t)p * ND + g * 8;
      }
    const bf16* pb0 = wte + ((size_t)e * NH + n0 + sr) * ND + g * 8;

#define srcA(t, h, rr) (pa[h][rr] + (size_t)(t) * 64)
#define srcB(t, h, rr) (pb0 + ((h) * 128 + (rr) * 64) * (size_t)ND + (size_t)(t) * 64)

    f32x4 acc[8][4] = {};
    bf16x8 af[4][2], bfr[4][2];
    const int NT = ND / 64;   // 16

    // prologue: tile0 (8 loads), tile1 (8 loads); wait tile0
    STAGE_A(0, 0); STAGE_A(0, 1); STAGE_B(0, 0); STAGE_B(0, 1);
    STAGE_A(1, 0); STAGE_A(1, 1); STAGE_B(1, 0); STAGE_B(1, 1);
    VMC8;
    BAR;

#pragma unroll 6
    for (int i = 0; i < NT - 2; i++)
        DO_TILE(i, STAGE_A(i + 2, 0), STAGE_A(i + 2, 1),
                   STAGE_B(i + 2, 0), STAGE_B(i + 2, 1), VMC8);
    DO_TILE(NT - 2, , , , , VMC0);
    DO_TILE(NT - 1, , , , , );

    // epilogue: bias + relu, bf16, permuted (dense) row order
    float bias[4];
#pragma unroll
    for (int n = 0; n < 4; n++) bias[n] = b_e[e * NH + n0 + wc * 64 + n * 16 + lr];
#pragma unroll
    for (int m = 0; m < 8; m++) {
#pragma unroll
        for (int rr = 0; rr < 4; rr++) {
            int row = wr * 128 + m * 16 + kg * 4 + rr;
            if (row < rc) {
                bf16* hp = hb + (size_t)(rs + row) * NH + n0 + wc * 64;
#pragma unroll
                for (int n = 0; n < 4; n++)
                    hp[n * 16 + lr] = (bf16)fmaxf(acc[m][n][rr] + bias[n], 0.0f);
            }
        }
    }
#undef srcA
#undef srcB
}

__launch_bounds__(512, 2)
__global__ void k_gemm2(const bf16* __restrict__ hb, const bf16* __restrict__ wto,
                        const float* __restrict__ b_out, const int* __restrict__ meta,
                        float* __restrict__ out) {
    __shared__ __align__(16) char sm[163840];
    // bijective XCD swizzle over exactly 256 blocks (32 consecutive per XCD)
    int lin = blockIdx.x;
    int swz = (lin & 7) * 32 + (lin >> 3);
    int bx = swz & 3, by = swz >> 2;
    int m0 = by * 256, n0 = bx * 256;
    const int* perm = meta + 512;

    int tid = threadIdx.x;
    int lane = tid & 63, wid = tid >> 6;
    int wr = wid >> 2, wc = wid & 3;
    int lr = lane & 15, kg = lane >> 4;
    int xk0 = (kg ^ (lr & 7)) * 16;
    int xk1 = ((4 + kg) ^ (lr & 7)) * 16;

    int sr = tid >> 3, sl = tid & 7;
    int g = sl ^ (sr & 7);
    const bf16* pa0 = hb  + ((size_t)m0 + sr) * NH + g * 8;
    const bf16* pb0 = wto + ((size_t)n0 + sr) * NH + g * 8;

#define srcA(t, h, rr) (pa0 + ((h) * 128 + (rr) * 64) * (size_t)NH + (size_t)(t) * 64)
#define srcB(t, h, rr) (pb0 + ((h) * 128 + (rr) * 64) * (size_t)NH + (size_t)(t) * 64)

    f32x4 acc[8][4] = {};
    bf16x8 af[4][2], bfr[4][2];
    const int NT = NH / 64;   // 64

    STAGE_A(0, 0); STAGE_A(0, 1); STAGE_B(0, 0); STAGE_B(0, 1);
    STAGE_A(1, 0); STAGE_A(1, 1); STAGE_B(1, 0); STAGE_B(1, 1);
    VMC8;
    BAR;

#pragma unroll 6
    for (int i = 0; i < NT - 2; i++)
        DO_TILE(i, STAGE_A(i + 2, 0), STAGE_A(i + 2, 1),
                   STAGE_B(i + 2, 0), STAGE_B(i + 2, 1), VMC8);
    DO_TILE(NT - 2, , , , , VMC0);
    DO_TILE(NT - 1, , , , , );

    // epilogue: bias, scatter rows to token order via perm
    float bias[4];
#pragma unroll
    for (int n = 0; n < 4; n++) bias[n] = b_out[n0 + wc * 64 + n * 16 + lr];
#pragma unroll
    for (int m = 0; m < 8; m++) {
#pragma unroll
        for (int rr = 0; rr < 4; rr++) {
            int prow = m0 + wr * 128 + m * 16 + kg * 4 + rr;
            int tok = perm[prow];
            float* op = out + (size_t)tok * ND + n0 + wc * 64;
#pragma unroll
            for (int n = 0; n < 4; n++)
                op[n * 16 + lr] = acc[m][n][rr] + bias[n];
        }
    }
#undef srcA
#undef srcB
}

extern "C" void kernel_launch(void* const* d_in, const int* in_sizes, int n_in,
                              void* d_out, int out_size, void* d_ws, size_t ws_size,
                              hipStream_t stream) {
    const float* x     = (const float*)d_in[0];
    const float* W_e   = (const float*)d_in[1];
    const float* b_e   = (const float*)d_in[2];
    const float* W_out = (const float*)d_in[3];
    const float* b_out = (const float*)d_in[4];
    const int*   assign = (const int*)d_in[5];
    float* out = (float*)d_out;

    if (ws_size < WS_NEED) return;

    char* ws = (char*)d_ws;
    int*  meta = (int*)ws;
    bf16* xbp = (bf16*)(ws + OFF_XB);
    bf16* wte = (bf16*)(ws + OFF_WTE);
    bf16* wto = (bf16*)(ws + OFF_WTO);
    bf16* hb  = (bf16*)(ws + OFF_HB);

    k_route<<<1, 1024, 0, stream>>>(assign, meta);
    k_gather_cvt<<<NTOK * ND / (256 * 8), 256, 0, stream>>>(x, meta, xbp);
    k_transpose<<<dim3(NH / 32, ND / 32, NE), dim3(32, 8), 0, stream>>>(W_e, wte, ND, NH);
    k_transpose<<<dim3(ND / 32, NH / 32, 1), dim3(32, 8), 0, stream>>>(W_out, wto, NH, ND);
    // grouped GEMM1: 8 experts x 9 tiles x 16 n-panels; expert == XCD
    k_gemm1<<<1152, 512, 0, stream>>>(xbp, wte, b_e, hb, meta);
    // dense GEMM2 over permuted hb rows, scatter at the end
    k_gemm2<<<256, 512, 0, stream>>>(hb, wto, b_out, meta, out);
}

// Round 6
// 438.014 us; speedup vs baseline: 1.5688x; 1.0117x over previous
//
#include <hip/hip_runtime.h>
#include <hip/hip_bf16.h>
#include <stdint.h>

// Problem dims (fixed)
#define NB 8
#define NS 2048
#define ND 1024
#define NH 4096
#define NE 8
#define NTOK (NB*NS)   // 16384 tokens

typedef __bf16 bf16;
typedef bf16 bf16x8 __attribute__((ext_vector_type(8)));
typedef float f32x4 __attribute__((ext_vector_type(4)));

// ws layout: meta[512] ints + perm[16384] at meta+512, then:
static const size_t OFF_XB  = 128 * 1024;                          // bf16 xbp[NTOK][ND]  (PERMUTED rows)
static const size_t OFF_WTE = OFF_XB  + (size_t)NTOK * ND * 2;     // bf16 wte[NE][NH][ND]
static const size_t OFF_WTO = OFF_WTE + (size_t)NE * NH * ND * 2;  // bf16 wto[ND][NH]
static const size_t OFF_HB  = OFF_WTO + (size_t)ND * NH * 2;       // bf16 hb [NTOK][NH] (permuted rows)
static const size_t WS_NEED = OFF_HB  + (size_t)NTOK * NH * 2;

#define GLDS16(src, dst) __builtin_amdgcn_global_load_lds( \
    (__attribute__((address_space(1))) void*)(void*)(src), \
    (__attribute__((address_space(3))) void*)(dst), 16, 0, 0)

// ---------------- prep kernels ----------------

// fused routing: histogram + prefix + scatter, ONE block (1024 thr)
__global__ void k_route(const int* __restrict__ assign, int* __restrict__ meta) {
    __shared__ int cnt[NE];
    __shared__ int offs_s[NE];
    int tid = threadIdx.x;
    if (tid < NE) cnt[tid] = 0;
    __syncthreads();
    for (int t = tid; t < NTOK; t += 1024) atomicAdd(&cnt[assign[t] & 7], 1);
    __syncthreads();
    if (tid == 0) {
        int o = 0;
        for (int e = 0; e < NE; e++) {
            meta[e] = cnt[e]; meta[16 + e] = o; offs_s[e] = o; o += cnt[e];
        }
    }
    __syncthreads();
    if (tid < NE) cnt[tid] = offs_s[tid];   // reuse as cursors
    __syncthreads();
    int* perm = meta + 512;
    for (int t = tid; t < NTOK; t += 1024) {
        int e = assign[t] & 7;
        int p = atomicAdd(&cnt[e], 1);
        perm[p] = t;
    }
}

// gather + f32->bf16: xbp[p][:] = bf16(x[perm[p]][:])
__global__ void k_gather_cvt(const float* __restrict__ x, const int* __restrict__ meta,
                             bf16* __restrict__ xbp) {
    long i = (long)blockIdx.x * blockDim.x + threadIdx.x;   // 8 elems each
    int row = (int)(i >> 7);      // ND/8 = 128 chunks per row
    int c8  = (int)(i & 127);
    const int* perm = meta + 512;
    int tok = perm[row];
    const float4* s = (const float4*)(x + (size_t)tok * ND + c8 * 8);
    float4 v0 = s[0], v1 = s[1];
    bf16x8 o;
    o[0] = (bf16)v0.x; o[1] = (bf16)v0.y; o[2] = (bf16)v0.z; o[3] = (bf16)v0.w;
    o[4] = (bf16)v1.x; o[5] = (bf16)v1.y; o[6] = (bf16)v1.z; o[7] = (bf16)v1.w;
    *(bf16x8*)(xbp + i * 8) = o;
}

// transpose+convert: in [batch][R][C] f32 -> out [batch][C][R] bf16
__global__ void k_transpose(const float* __restrict__ in, bf16* __restrict__ out,
                            int R, int C) {
    __shared__ float tile[32][33];
    int b  = blockIdx.z;
    int c0 = blockIdx.x * 32, r0 = blockIdx.y * 32;
    const float* inb = in + (size_t)b * R * C;
    bf16* outb = out + (size_t)b * R * C;
    int tx = threadIdx.x, ty = threadIdx.y;
#pragma unroll
    for (int i = 0; i < 4; i++) {
        int r = r0 + ty + i * 8;
        tile[ty + i * 8][tx] = inb[(size_t)r * C + c0 + tx];
    }
    __syncthreads();
#pragma unroll
    for (int i = 0; i < 4; i++) {
        int c = c0 + ty + i * 8;
        outb[(size_t)c * R + r0 + tx] = (bf16)tile[tx][ty + i * 8];
    }
}

// =====================================================================
// 8-phase 256x256 GEMM, BK=64, 8 waves (2Mx4N), deep pipeline:
//  A: 3-deep buffers (stage i+2), B: 2-deep (stage i+2), vmcnt(8)/K-tile.
// LDS 160KB: A [0,96K) = 3 x (h0 16K | h1 16K); B [96K,160K) = 2 x 32K.
// Region = 128 rows x 64 k bf16, row stride 128B; slot s of row r holds
// global granule s ^ (r&7)  (bank-balanced XOR swizzle, conflict-free).
// =====================================================================

#define BAR { __builtin_amdgcn_s_barrier(); asm volatile("" ::: "memory"); }
#define VMC8 asm volatile("s_waitcnt vmcnt(8)" ::: "memory")
#define VMC0 asm volatile("s_waitcnt vmcnt(0)" ::: "memory")

#define LDA(msub) { \
  const char* Ab = sm + abuf + wr * 16384; \
  _Pragma("unroll") for (int m = 0; m < 4; m++) { \
    int row = ((msub) * 4 + m) * 16 + lr; \
    af[m][0] = *(const bf16x8*)(Ab + row * 128 + xk0); \
    af[m][1] = *(const bf16x8*)(Ab + row * 128 + xk1); \
  } }

#define LDB(nsub) { \
  const char* Bb = sm + bbuf + (wc >> 1) * 16384; \
  _Pragma("unroll") for (int n = 0; n < 2; n++) { \
    int row = (wc & 1) * 64 + ((nsub) * 2 + n) * 16 + lr; \
    bfr[(nsub)*2+n][0] = *(const bf16x8*)(Bb + row * 128 + xk0); \
    bfr[(nsub)*2+n][1] = *(const bf16x8*)(Bb + row * 128 + xk1); \
  } }

#define MFMA_Q(msub, nsub) { \
  __builtin_amdgcn_s_setprio(1); \
  _Pragma("unroll") for (int m = 0; m < 4; m++) \
  _Pragma("unroll") for (int n = 0; n < 2; n++) \
  _Pragma("unroll") for (int k = 0; k < 2; k++) \
    acc[(msub)*4+m][(nsub)*2+n] = __builtin_amdgcn_mfma_f32_16x16x32_bf16( \
        af[m][k], bfr[(nsub)*2+n][k], acc[(msub)*4+m][(nsub)*2+n], 0, 0, 0); \
  __builtin_amdgcn_s_setprio(0); }

#define DO_TILE(i, S0, S1, S2, S3, VW) { \
  const int abuf = ((i) % 3) * 32768; \
  const int bbuf = 98304 + ((i) & 1) * 32768; \
  LDA(0); LDB(0); S0; BAR; MFMA_Q(0,0); BAR; \
  LDB(1);         S1; BAR; MFMA_Q(0,1); BAR; \
  LDA(1);         S2; BAR; MFMA_Q(1,0); BAR; \
                  S3; VW; BAR; MFMA_Q(1,1); BAR; \
}

// STAGE macros (shared by both gemms; define srcA/srcB first)
#define STAGE_A(t, h) { \
    char* d = sm + ((t) % 3) * 32768 + (h) * 16384 + wid * 1024; \
    GLDS16(srcA(t, h, 0), d); \
    GLDS16(srcA(t, h, 1), d + 8192); }
#define STAGE_B(t, h) { \
    char* d = sm + 98304 + ((t) & 1) * 32768 + (h) * 16384 + wid * 1024; \
    GLDS16(srcB(t, h, 0), d); \
    GLDS16(srcB(t, h, 1), d + 8192); }

__launch_bounds__(512, 2)
__global__ void k_gemm1(const bf16* __restrict__ xbp, const bf16* __restrict__ wte,
                        const float* __restrict__ b_e, bf16* __restrict__ hb,
                        const int* __restrict__ meta) {
    __shared__ __align__(16) char sm[163840];
    // expert == XCD (f & 7); within an XCD, j is FASTEST so the same B-panel
    // (e, bx) is read by 9 temporally-adjacent blocks (L2 reuse; 4 panels =
    // 2MB fits L2), A-tiles shared 4-way across concurrent bx groups.
    int f = blockIdx.x;
    int e = f & 7, q = f >> 3;
    int j = q % 9, bx = q / 9;               // j = m-tile 0..8, bx = n-panel 0..15
    int cnt = meta[e];
    int rs  = meta[16 + e] + j * 256;
    int rc  = cnt - j * 256; if (rc > 256) rc = 256;
    if (rc <= 0) return;
    int n0 = bx * 256;

    int tid = threadIdx.x;
    int lane = tid & 63, wid = tid >> 6;
    int wr = wid >> 2, wc = wid & 3;
    int lr = lane & 15, kg = lane >> 4;
    int xk0 = (kg ^ (lr & 7)) * 16;
    int xk1 = ((4 + kg) ^ (lr & 7)) * 16;

    int sr = tid >> 3, sl = tid & 7;
    int g = sl ^ (sr & 7);
    const bf16* pa[2][2];
#pragma unroll
    for (int h = 0; h < 2; h++)
#pragma unroll
      for (int rr = 0; rr < 2; rr++) {
        int arow = h * 128 + rr * 64 + sr;
        int p = rs + (arow < rc - 1 ? arow : rc - 1);
        pa[h][rr] = xbp + (size_t)p * ND + g * 8;
      }
    const bf16* pb0 = wte + ((size_t)e * NH + n0 + sr) * ND + g * 8;

#define srcA(t, h, rr) (pa[h][rr] + (size_t)(t) * 64)
#define srcB(t, h, rr) (pb0 + ((h) * 128 + (rr) * 64) * (size_t)ND + (size_t)(t) * 64)

    f32x4 acc[8][4] = {};
    bf16x8 af[4][2], bfr[4][2];
    const int NT = ND / 64;   // 16

    // prologue: tile0 (8 loads), tile1 (8 loads); wait tile0
    STAGE_A(0, 0); STAGE_A(0, 1); STAGE_B(0, 0); STAGE_B(0, 1);
    STAGE_A(1, 0); STAGE_A(1, 1); STAGE_B(1, 0); STAGE_B(1, 1);
    VMC8;
    BAR;

#pragma unroll 6
    for (int i = 0; i < NT - 2; i++)
        DO_TILE(i, STAGE_A(i + 2, 0), STAGE_A(i + 2, 1),
                   STAGE_B(i + 2, 0), STAGE_B(i + 2, 1), VMC8);
    DO_TILE(NT - 2, , , , , VMC0);
    DO_TILE(NT - 1, , , , , );

    // epilogue: bias + relu, bf16, permuted (dense) row order
    float bias[4];
#pragma unroll
    for (int n = 0; n < 4; n++) bias[n] = b_e[e * NH + n0 + wc * 64 + n * 16 + lr];
#pragma unroll
    for (int m = 0; m < 8; m++) {
#pragma unroll
        for (int rr = 0; rr < 4; rr++) {
            int row = wr * 128 + m * 16 + kg * 4 + rr;
            if (row < rc) {
                bf16* hp = hb + (size_t)(rs + row) * NH + n0 + wc * 64;
#pragma unroll
                for (int n = 0; n < 4; n++)
                    hp[n * 16 + lr] = (bf16)fmaxf(acc[m][n][rr] + bias[n], 0.0f);
            }
        }
    }
#undef srcA
#undef srcB
}

__launch_bounds__(512, 2)
__global__ void k_gemm2(const bf16* __restrict__ hb, const bf16* __restrict__ wto,
                        const float* __restrict__ b_out, const int* __restrict__ meta,
                        float* __restrict__ out) {
    __shared__ __align__(16) char sm[163840];
    // bijective XCD swizzle over exactly 256 blocks: per XCD 8m x 4n super-tile
    int lin = blockIdx.x;
    int swz = (lin & 7) * 32 + (lin >> 3);
    int bx = swz & 3, by = swz >> 2;
    int m0 = by * 256, n0 = bx * 256;
    const int* perm = meta + 512;

    int tid = threadIdx.x;
    int lane = tid & 63, wid = tid >> 6;
    int wr = wid >> 2, wc = wid & 3;
    int lr = lane & 15, kg = lane >> 4;
    int xk0 = (kg ^ (lr & 7)) * 16;
    int xk1 = ((4 + kg) ^ (lr & 7)) * 16;

    int sr = tid >> 3, sl = tid & 7;
    int g = sl ^ (sr & 7);
    const bf16* pa0 = hb  + ((size_t)m0 + sr) * NH + g * 8;
    const bf16* pb0 = wto + ((size_t)n0 + sr) * NH + g * 8;

#define srcA(t, h, rr) (pa0 + ((h) * 128 + (rr) * 64) * (size_t)NH + (size_t)(t) * 64)
#define srcB(t, h, rr) (pb0 + ((h) * 128 + (rr) * 64) * (size_t)NH + (size_t)(t) * 64)

    f32x4 acc[8][4] = {};
    bf16x8 af[4][2], bfr[4][2];
    const int NT = NH / 64;   // 64

    STAGE_A(0, 0); STAGE_A(0, 1); STAGE_B(0, 0); STAGE_B(0, 1);
    STAGE_A(1, 0); STAGE_A(1, 1); STAGE_B(1, 0); STAGE_B(1, 1);
    VMC8;
    BAR;

#pragma unroll 6
    for (int i = 0; i < NT - 2; i++)
        DO_TILE(i, STAGE_A(i + 2, 0), STAGE_A(i + 2, 1),
                   STAGE_B(i + 2, 0), STAGE_B(i + 2, 1), VMC8);
    DO_TILE(NT - 2, , , , , VMC0);
    DO_TILE(NT - 1, , , , , );

    // epilogue: bias, scatter rows to token order via perm
    float bias[4];
#pragma unroll
    for (int n = 0; n < 4; n++) bias[n] = b_out[n0 + wc * 64 + n * 16 + lr];
#pragma unroll
    for (int m = 0; m < 8; m++) {
#pragma unroll
        for (int rr = 0; rr < 4; rr++) {
            int prow = m0 + wr * 128 + m * 16 + kg * 4 + rr;
            int tok = perm[prow];
            float* op = out + (size_t)tok * ND + n0 + wc * 64;
#pragma unroll
            for (int n = 0; n < 4; n++)
                op[n * 16 + lr] = acc[m][n][rr] + bias[n];
        }
    }
#undef srcA
#undef srcB
}

extern "C" void kernel_launch(void* const* d_in, const int* in_sizes, int n_in,
                              void* d_out, int out_size, void* d_ws, size_t ws_size,
                              hipStream_t stream) {
    const float* x     = (const float*)d_in[0];
    const float* W_e   = (const float*)d_in[1];
    const float* b_e   = (const float*)d_in[2];
    const float* W_out = (const float*)d_in[3];
    const float* b_out = (const float*)d_in[4];
    const int*   assign = (const int*)d_in[5];
    float* out = (float*)d_out;

    if (ws_size < WS_NEED) return;

    char* ws = (char*)d_ws;
    int*  meta = (int*)ws;
    bf16* xbp = (bf16*)(ws + OFF_XB);
    bf16* wte = (bf16*)(ws + OFF_WTE);
    bf16* wto = (bf16*)(ws + OFF_WTO);
    bf16* hb  = (bf16*)(ws + OFF_HB);

    k_route<<<1, 1024, 0, stream>>>(assign, meta);
    k_gather_cvt<<<NTOK * ND / (256 * 8), 256, 0, stream>>>(x, meta, xbp);
    k_transpose<<<dim3(NH / 32, ND / 32, NE), dim3(32, 8), 0, stream>>>(W_e, wte, ND, NH);
    k_transpose<<<dim3(ND / 32, NH / 32, 1), dim3(32, 8), 0, stream>>>(W_out, wto, NH, ND);
    // grouped GEMM1: 8 experts (==XCD) x (9 j FASTEST x 16 bx)
    k_gemm1<<<1152, 512, 0, stream>>>(xbp, wte, b_e, hb, meta);
    // dense GEMM2 over permuted hb rows, scatter at the end
    k_gemm2<<<256, 512, 0, stream>>>(hb, wto, b_out, meta, out);
}